// Round 1
// baseline (201.234 us; speedup 1.0000x reference)
//
#include <hip/hip_runtime.h>

// Problem constants (from reference setup_inputs): B=2, C=16, D=64, H=128, W=128
#define BB 2
#define CC 16
#define SEGS (BB * CC)          // 32 (b,c) segments
#define REPS 64                 // replicated accumulator banks (1 cache line each)
#define NVOX (64 * 128 * 128)   // voxels per batch = 1048576 = 2^20
#define N4   (NVOX / 4)         // float4-granular voxels per batch = 262144 = 2^18

// Zero the 64 replicas x 32 segments of sum/count accumulators (re-poisoned 0xAA each replay).
__global__ void cwce_init(float* __restrict__ ws_sum, unsigned* __restrict__ ws_cnt) {
    const int t = threadIdx.x;  // 256 threads, 8 iters -> 2048 entries each
#pragma unroll
    for (int i = 0; i < (REPS * SEGS) / 256; ++i) {
        ws_sum[t + i * 256] = 0.0f;
        ws_cnt[t + i * 256] = 0u;
    }
}

// Main pass: one thread = 4 consecutive voxels. 16 float4 loads (one per class,
// 16B/lane fully coalesced), register log-sum-exp, LDS-atomic class accumulation,
// then 32 global atomics per block into a 64-way REPLICATED accumulator:
// replica = blockIdx & 63, so same-line atomic contention is 2048/64 = 32 blocks
// per 128B line instead of 2048 blocks on ONE line (the previous serial convoy).
__global__ __launch_bounds__(256) void cwce_main(const float* __restrict__ x,
                                                 const int* __restrict__ y,
                                                 float* __restrict__ ws_sum,
                                                 unsigned* __restrict__ ws_cnt) {
    __shared__ float    s_sum[CC];
    __shared__ unsigned s_cnt[CC];
    const int t = threadIdx.x;
    if (t < CC) { s_sum[t] = 0.0f; s_cnt[t] = 0u; }
    __syncthreads();

    const unsigned gid = blockIdx.x * 256u + t;      // [0, 524288)
    const unsigned b   = gid >> 18;                  // 262144 threads per batch
    const unsigned n4  = gid & (N4 - 1);

    const float4* xb = (const float4*)x + (size_t)(b * CC) * N4 + n4;
    const int4 lab4 = ((const int4*)y)[gid];

    // Load the full 16-class x 4-voxel tile into registers (one HBM pass).
    float xv[CC][4];
#pragma unroll
    for (int c = 0; c < CC; ++c) {
        float4 v = xb[(size_t)c * N4];
        xv[c][0] = v.x; xv[c][1] = v.y; xv[c][2] = v.z; xv[c][3] = v.w;
    }
    const int labs[4] = {lab4.x, lab4.y, lab4.z, lab4.w};

#pragma unroll
    for (int j = 0; j < 4; ++j) {
        float m = xv[0][j];
#pragma unroll
        for (int c = 1; c < CC; ++c) m = fmaxf(m, xv[c][j]);
        const int lj = labs[j];
        float s = 0.0f, xy = 0.0f;
#pragma unroll
        for (int c = 0; c < CC; ++c) {
            s += __expf(xv[c][j] - m);
            if (c == lj) xy = xv[c][j];   // cndmask select of x[label]
        }
        const float nll = m + __logf(s) - xy;
        atomicAdd(&s_sum[lj], nll);
        atomicAdd(&s_cnt[lj], 1u);
    }
    __syncthreads();

    // Block covers 1024 contiguous voxels -> single batch b; 16 segments live here.
    // Scatter into replica (blockIdx & 63): each replica's 32 floats = own 128B line,
    // 64 sum-lines + 64 cnt-lines spread across L2 slices -> parallel atomic streams.
    if (t < CC) {
        const unsigned rep = blockIdx.x & (REPS - 1);
        atomicAdd(&ws_sum[rep * SEGS + b * CC + t], s_sum[t]);
        atomicAdd(&ws_cnt[rep * SEGS + b * CC + t], s_cnt[t]);
    }
}

// Final: reduce 64 replicas -> per-(b,c) mean (empty class -> 0), then sum/(B*C). One block.
__global__ void cwce_final(const float* __restrict__ ws_sum,
                           const unsigned* __restrict__ ws_cnt,
                           float* __restrict__ out) {
    __shared__ float ps[8][SEGS];
    __shared__ float pc[8][SEGS];
    const int t   = threadIdx.x;   // 256 threads
    const int seg = t & 31;
    const int g   = t >> 5;        // 8 groups, each owns 8 replicas
    float s = 0.0f, c = 0.0f;
#pragma unroll
    for (int k = 0; k < 8; ++k) {
        const int rep = g + k * 8;                 // covers replicas 0..63
        s += ws_sum[rep * SEGS + seg];
        c += (float)ws_cnt[rep * SEGS + seg];      // counts < 2^24: exact in float
    }
    ps[g][seg] = s;
    pc[g][seg] = c;
    __syncthreads();

    if (t < 64) {                  // first wave finishes: cross-group reduce + mean + sum
        float v = 0.0f;
        if (t < SEGS) {
            float ts = 0.0f, tc = 0.0f;
#pragma unroll
            for (int gg = 0; gg < 8; ++gg) { ts += ps[gg][t]; tc += pc[gg][t]; }
            v = (tc > 0.0f) ? (ts / tc) : 0.0f;    // absent class contributes 0
        }
#pragma unroll
        for (int off = 32; off >= 1; off >>= 1) v += __shfl_down(v, off);
        if (t == 0) out[0] = v * (1.0f / SEGS);
    }
}

extern "C" void kernel_launch(void* const* d_in, const int* in_sizes, int n_in,
                              void* d_out, int out_size, void* d_ws, size_t ws_size,
                              hipStream_t stream) {
    const float* x = (const float*)d_in[0];
    const int*   y = (const int*)d_in[1];
    float*       out = (float*)d_out;

    float*    ws_sum = (float*)d_ws;                       // 64*32 floats  (8 KB)
    unsigned* ws_cnt = (unsigned*)(ws_sum + REPS * SEGS);  // 64*32 uints   (8 KB)

    cwce_init<<<1, 256, 0, stream>>>(ws_sum, ws_cnt);
    // total threads = B * NVOX / 4 = 524288 -> 2048 blocks of 256
    cwce_main<<<2048, 256, 0, stream>>>(x, y, ws_sum, ws_cnt);
    cwce_final<<<1, 256, 0, stream>>>(ws_sum, ws_cnt, out);
}

// Round 2
// 196.817 us; speedup vs baseline: 1.0224x; 1.0224x over previous
//
#include <hip/hip_runtime.h>

// Problem constants (from reference setup_inputs): B=2, C=16, D=64, H=128, W=128
#define BB 2
#define CC 16
#define SEGS (BB * CC)          // 32 (b,c) segments
#define NVOX (64 * 128 * 128)   // voxels per batch = 1048576 = 2^20
#define N4   (NVOX / 4)         // float4-granular voxels per batch = 262144 = 2^18
#define NBLK 2048               // main-pass blocks (B * NVOX / 4 / 256)

typedef float v4f __attribute__((ext_vector_type(4)));

// Main pass: one thread = 4 consecutive voxels. 16 nontemporal float4 loads (one per
// class, 16B/lane fully coalesced), register log-sum-exp, LDS-atomic class
// accumulation, then NON-ATOMIC per-block partial stores. Every partial slot is
// written unconditionally -> no init kernel needed despite 0xAA workspace poison.
__global__ __launch_bounds__(256) void cwce_main(const float* __restrict__ x,
                                                 const int* __restrict__ y,
                                                 float* __restrict__ part_sum,
                                                 unsigned* __restrict__ part_cnt) {
    __shared__ float    s_sum[CC];
    __shared__ unsigned s_cnt[CC];
    const int t = threadIdx.x;
    if (t < CC) { s_sum[t] = 0.0f; s_cnt[t] = 0u; }
    __syncthreads();

    const unsigned gid = blockIdx.x * 256u + t;      // [0, 524288)
    const unsigned b   = gid >> 18;                  // 262144 threads per batch
    const unsigned n4  = gid & (N4 - 1);

    const v4f* xb = (const v4f*)x + (size_t)(b * CC) * N4 + n4;
    const int4 lab4 = ((const int4*)y)[gid];

    // Load the full 16-class x 4-voxel tile into registers (one HBM pass).
    // Nontemporal: x is strictly single-use streaming data.
    float xv[CC][4];
#pragma unroll
    for (int c = 0; c < CC; ++c) {
        v4f v = __builtin_nontemporal_load(xb + (size_t)c * N4);
        xv[c][0] = v.x; xv[c][1] = v.y; xv[c][2] = v.z; xv[c][3] = v.w;
    }
    const int labs[4] = {lab4.x, lab4.y, lab4.z, lab4.w};

#pragma unroll
    for (int j = 0; j < 4; ++j) {
        float m = xv[0][j];
#pragma unroll
        for (int c = 1; c < CC; ++c) m = fmaxf(m, xv[c][j]);
        const int lj = labs[j];
        float s = 0.0f, xy = 0.0f;
#pragma unroll
        for (int c = 0; c < CC; ++c) {
            s += __expf(xv[c][j] - m);
            if (c == lj) xy = xv[c][j];   // cndmask select of x[label]
        }
        const float nll = m + __logf(s) - xy;
        atomicAdd(&s_sum[lj], nll);
        atomicAdd(&s_cnt[lj], 1u);
    }
    __syncthreads();

    // Per-block partials, no atomics: slot [blockIdx][c]. All 2048*16 slots are
    // written every launch, so the 0xAA re-poison never needs a zeroing pass.
    if (t < CC) {
        part_sum[blockIdx.x * CC + t] = s_sum[t];
        part_cnt[blockIdx.x * CC + t] = s_cnt[t];
    }
}

// Final: reduce 2048x16 partials -> per-(b,c) mean (empty class -> 0), then
// sum/(B*C). One block of 256 threads; reads 256 KB of partials.
__global__ void cwce_final(const float* __restrict__ part_sum,
                           const unsigned* __restrict__ part_cnt,
                           float* __restrict__ out) {
    __shared__ float fs[16][CC];
    __shared__ float fc[16][CC];
    const int t = threadIdx.x;     // 256 threads
    const int c = t & 15;          // class
    const int g = t >> 4;          // 16 groups; group g owns block-rows [g*128,(g+1)*128)
    float s = 0.0f, n = 0.0f;
    for (int r = g * 128; r < (g + 1) * 128; ++r) {
        s += part_sum[r * CC + c];
        n += (float)part_cnt[r * CC + c];   // counts < 2^24: exact in float
    }
    fs[g][c] = s;
    fc[g][c] = n;
    __syncthreads();

    // Block-rows [0,1024) are batch 0, [1024,2048) batch 1 -> groups g<8 are b=0,
    // g>=8 are b=1. Thread t<32 finishes segment (b=t>>4, c=t&15).
    if (t < 64) {                  // whole first wave participates in the shfl tree
        float v = 0.0f;
        if (t < SEGS) {
            const int b = t >> 4;
            float ts = 0.0f, tn = 0.0f;
#pragma unroll
            for (int k = 0; k < 8; ++k) { ts += fs[b * 8 + k][c]; tn += fc[b * 8 + k][c]; }
            v = (tn > 0.0f) ? (ts / tn) : 0.0f;   // absent class contributes 0
        }
#pragma unroll
        for (int off = 32; off >= 1; off >>= 1) v += __shfl_down(v, off);
        if (t == 0) out[0] = v * (1.0f / SEGS);
    }
}

extern "C" void kernel_launch(void* const* d_in, const int* in_sizes, int n_in,
                              void* d_out, int out_size, void* d_ws, size_t ws_size,
                              hipStream_t stream) {
    const float* x = (const float*)d_in[0];
    const int*   y = (const int*)d_in[1];
    float*       out = (float*)d_out;

    float*    part_sum = (float*)d_ws;                         // 2048*16 floats (128 KB)
    unsigned* part_cnt = (unsigned*)(part_sum + NBLK * CC);    // 2048*16 uints  (128 KB)

    // total threads = B * NVOX / 4 = 524288 -> 2048 blocks of 256. No init kernel.
    cwce_main<<<NBLK, 256, 0, stream>>>(x, y, part_sum, part_cnt);
    cwce_final<<<1, 256, 0, stream>>>(part_sum, part_cnt, out);
}